// Round 12
// baseline (127.510 us; speedup 1.0000x reference)
//
#include <hip/hip_runtime.h>
#include <hip/hip_fp16.h>

// Warp: trilinear grid_sample, padding_mode='zeros', align_corners=true.
// image: (B=2, C=1, H=128, W=128, D=128) fp32
// ddf:   (B=2, 3, H, W, D) fp32 voxel displacements; out: (B,1,H,W,D) fp32
//
// R11 = 29.6us kernel; HBM duty ~50% (phase serialization). R12: x-adjacent
// tile pair per block; tile-B ddf + half of B's staging issued BEFORE
// compute-A and pinned with sched_barrier(0) so LLVM cannot sink the loads
// (R10 failure mode: VGPR=32 proved loads were sunk past the barrier).
// VGPR budget ~60 <= 64 so 2 blocks/CU (32 waves) is preserved.

constexpr int H = 128, W = 128, D = 128;
constexpr int N = H * W * D;      // 2^21
constexpr int B = 2;
constexpr int HA = 8;             // halo per side
constexpr int RS = 32;            // region edge
constexpr int RN = RS * RS * RS;  // 32768 fp16 = 64 KB

typedef float fvec4 __attribute__((ext_vector_type(4)));
typedef unsigned u2v __attribute__((ext_vector_type(2), aligned(4)));

__device__ __forceinline__ void stage_load(const float* __restrict__ img,
    int ox, int oy, int oz, int t, int c, fvec4& A, fvec4& Bv)
{
    int s   = c * 1024 + t;
    int row = s >> 2;             // rx*32 + ry
    int zo  = (s & 3) << 3;
    int gx = ox + (row >> 5);
    int gy = oy + (row & 31);
    int gz = oz + zo;             // oz ≡ 0 mod 8 -> chunk fully in or out
    bool ok = ((unsigned)gx < 128u) & ((unsigned)gy < 128u) & ((unsigned)gz < 121u);
    const float* p = img + (gx << 14) + (gy << 7) + gz;
    fvec4 z4 = {0.f, 0.f, 0.f, 0.f};
    A  = ok ? *(const fvec4*)p       : z4;
    Bv = ok ? *(const fvec4*)(p + 4) : z4;
}

__device__ __forceinline__ void stage_write(__half* __restrict__ tile,
    int t, int c, fvec4 A, fvec4 Bv)
{
    int s   = c * 1024 + t;
    int row = s >> 2;
    int zo  = (s & 3) << 3;
    __half2 h0 = __floats2half2_rn(A.x, A.y);
    __half2 h1 = __floats2half2_rn(A.z, A.w);
    __half2 h2 = __floats2half2_rn(Bv.x, Bv.y);
    __half2 h3 = __floats2half2_rn(Bv.z, Bv.w);
    uint4 pk;
    pk.x = *(unsigned int*)&h0;
    pk.y = *(unsigned int*)&h1;
    pk.z = *(unsigned int*)&h2;
    pk.w = *(unsigned int*)&h3;
    *(uint4*)((unsigned short*)tile + row * 32 + zo) = pk;  // ds_write_b128
}

__device__ __forceinline__ void compute_tile(const __half* __restrict__ tile,
    const float* __restrict__ img, float* __restrict__ outb,
    int vx, int vy, int vz, int lin0, int ox, int oy, int oz,
    fvec4 dx4, fvec4 dy4, fvec4 dz4)
{
    const unsigned int* cells = (const unsigned int*)tile;   // half2 cells
    float dxp[4] = {dx4.x, dx4.y, dx4.z, dx4.w};
    float dyp[4] = {dy4.x, dy4.y, dy4.z, dy4.w};
    float dzp[4] = {dz4.x, dz4.y, dz4.z, dz4.w};
    float res[4];

#pragma unroll
    for (int i = 0; i < 4; ++i) {
        float x = (float)vx + dxp[i];
        float y = (float)vy + dyp[i];
        float z = (float)(vz + i) + dzp[i];

        float xf = floorf(x), yf = floorf(y), zf = floorf(z);
        float fx = x - xf, fy = y - yf, fz = z - zf;
        int x0 = (int)xf, y0 = (int)yf, z0 = (int)zf;
        int rx = x0 - ox, ry = y0 - oy, rz = z0 - oz;

        float acc;
        if ((unsigned)rx <= 30u && (unsigned)ry <= 30u && (unsigned)rz <= 30u) {
            // fast path: staged zeros implement zero-padding exactly.
            int rowc = ((rx << 5) + ry) << 4;   // row * 16 cells
            int c  = rowc + (rz >> 1);
            int sh = (rz & 1) << 4;
            u2v q00 = *(const u2v*)(cells + c);
            u2v q01 = *(const u2v*)(cells + c + 16);
            u2v q10 = *(const u2v*)(cells + c + 512);
            u2v q11 = *(const u2v*)(cells + c + 528);

            float az0 = 1.f - fz;
            float zz[4];
            unsigned los[4] = {q00.x, q01.x, q10.x, q11.x};
            unsigned his[4] = {q00.y, q01.y, q10.y, q11.y};
#pragma unroll
            for (int p2 = 0; p2 < 4; ++p2) {
                unsigned long long v = ((unsigned long long)his[p2] << 32) | los[p2];
                unsigned pr = (unsigned)(v >> sh);
                __half2 hp = *(__half2*)&pr;
                float2 f2 = __half22float2(hp);
                zz[p2] = az0 * f2.x + fz * f2.y;
            }
            float ay0 = 1.f - fy;
            acc = (1.f - fx) * (ay0 * zz[0] + fy * zz[1]) +
                  fx         * (ay0 * zz[2] + fy * zz[3]);
        } else {
            // rare: exact fp32 global gather with zero-padding.
            int x1 = x0 + 1, y1 = y0 + 1, z1 = z0 + 1;
            bool vx0 = (unsigned)x0 < (unsigned)H;
            bool vx1 = (unsigned)x1 < (unsigned)H;
            bool vy0 = (unsigned)y0 < (unsigned)W;
            bool vy1 = (unsigned)y1 < (unsigned)W;
            bool vz0 = (unsigned)z0 < (unsigned)D;
            bool vz1 = (unsigned)z1 < (unsigned)D;
            float ax0 = vx0 ? (1.0f - fx) : 0.0f;
            float ax1 = vx1 ? fx          : 0.0f;
            float ay0 = vy0 ? (1.0f - fy) : 0.0f;
            float ay1 = vy1 ? fy          : 0.0f;
            float az0 = vz0 ? (1.0f - fz) : 0.0f;
            float az1 = vz1 ? fz          : 0.0f;
            int cx0 = vx0 ? x0 : 0;
            int cx1 = vx1 ? x1 : 0;
            int cy0 = vy0 ? y0 : 0;
            int cy1 = vy1 ? y1 : 0;
            int cz0 = vz0 ? z0 : 0;
            int cz1 = vz1 ? z1 : 0;
            int rx0 = cx0 << 14, rx1 = cx1 << 14;
            int ry0 = cy0 << 7,  ry1 = cy1 << 7;
            float v000 = img[rx0 + ry0 + cz0];
            float v001 = img[rx0 + ry0 + cz1];
            float v010 = img[rx0 + ry1 + cz0];
            float v011 = img[rx0 + ry1 + cz1];
            float v100 = img[rx1 + ry0 + cz0];
            float v101 = img[rx1 + ry0 + cz1];
            float v110 = img[rx1 + ry1 + cz0];
            float v111 = img[rx1 + ry1 + cz1];
            acc = ax0 * (ay0 * (az0 * v000 + az1 * v001) +
                         ay1 * (az0 * v010 + az1 * v011)) +
                  ax1 * (ay0 * (az0 * v100 + az1 * v101) +
                         ay1 * (az0 * v110 + az1 * v111));
        }
        res[i] = acc;
    }
    fvec4 r4 = {res[0], res[1], res[2], res[3]};
    __builtin_nontemporal_store(r4, (fvec4*)(outb + lin0));
}

__global__ __launch_bounds__(1024, 8) void warp_pairx_kernel(
    const float* __restrict__ image,
    const float* __restrict__ ddf,
    float* __restrict__ out)
{
    __shared__ __half tile[RN];   // 64 KB -> 2 blocks/CU

    // XCD slab swizzle over 512 pair-blocks: XCD k owns P in [k*64,(k+1)*64)
    // = one (batch, x-pair) slab (~3.1 MB region -> fits 4 MB per-XCD L2).
    int bid = blockIdx.x;
    int P   = (bid & 7) * 64 + (bid >> 3);
    int b   = P >> 8;
    int pp  = P & 255;
    int px  = (pp >> 6) & 3;      // x-pair index
    int ty0 = ((pp >> 3) & 7) << 4;
    int tz0 = (pp & 7) << 4;
    int txA = (px << 1) << 4;     // tile A x-origin
    int txB = txA + 16;           // tile B x-origin (x-adjacent)
    int oy = ty0 - HA, oz = tz0 - HA;
    int oxA = txA - HA, oxB = txB - HA;

    const float* img  = image + ((size_t)b << 21);
    const float* ddfb = ddf + (size_t)b * 3 * N;
    float* outb = out + ((size_t)b << 21);
    int t = threadIdx.x;

    // thread -> 4 consecutive z voxels of each tile
    int zq = (t & 3) << 2;
    int ly = (t >> 2) & 15;
    int lx = t >> 6;
    int vy = ty0 + ly, vz = tz0 + zq;
    int vxA = txA + lx, vxB = txB + lx;
    int linA = (vxA << 14) + (vy << 7) + vz;
    int linB = linA + (16 << 14);

    // ---- tile A: ddf + full stage ----
    fvec4 adx = *(const fvec4*)(ddfb + linA);
    fvec4 ady = *(const fvec4*)(ddfb + linA + N);
    fvec4 adz = *(const fvec4*)(ddfb + linA + 2 * N);
    fvec4 s0, s1, s2, s3, u0, u1, u2, u3;
    stage_load(img, oxA, oy, oz, t, 0, s0, u0);
    stage_load(img, oxA, oy, oz, t, 1, s1, u1);
    stage_load(img, oxA, oy, oz, t, 2, s2, u2);
    stage_load(img, oxA, oy, oz, t, 3, s3, u3);
    stage_write(tile, t, 0, s0, u0);
    stage_write(tile, t, 1, s1, u1);
    stage_write(tile, t, 2, s2, u2);
    stage_write(tile, t, 3, s3, u3);

    // ---- tile B prefetch: ddf + first half of stage (pinned) ----
    fvec4 bdx = *(const fvec4*)(ddfb + linB);
    fvec4 bdy = *(const fvec4*)(ddfb + linB + N);
    fvec4 bdz = *(const fvec4*)(ddfb + linB + 2 * N);
    stage_load(img, oxB, oy, oz, t, 0, s0, u0);
    stage_load(img, oxB, oy, oz, t, 1, s1, u1);
    __builtin_amdgcn_sched_barrier(0);   // pin: loads may not sink below

    __syncthreads();
    compute_tile(tile, img, outb, vxA, vy, vz, linA, oxA, oy, oz, adx, ady, adz);

    // second half of B staging
    stage_load(img, oxB, oy, oz, t, 2, s2, u2);
    stage_load(img, oxB, oy, oz, t, 3, s3, u3);

    __syncthreads();              // all waves done reading tile A
    stage_write(tile, t, 0, s0, u0);
    stage_write(tile, t, 1, s1, u1);
    stage_write(tile, t, 2, s2, u2);
    stage_write(tile, t, 3, s3, u3);
    __syncthreads();

    compute_tile(tile, img, outb, vxB, vy, vz, linB, oxB, oy, oz, bdx, bdy, bdz);
}

extern "C" void kernel_launch(void* const* d_in, const int* in_sizes, int n_in,
                              void* d_out, int out_size, void* d_ws, size_t ws_size,
                              hipStream_t stream) {
    const float* image = (const float*)d_in[0];
    const float* ddf   = (const float*)d_in[1];
    float* out = (float*)d_out;

    warp_pairx_kernel<<<512, 1024, 0, stream>>>(image, ddf, out);
}